// Round 11
// baseline (190.814 us; speedup 1.0000x reference)
//
#include <hip/hip_runtime.h>
#include <math.h>

#define EMBED   64
#define HIDDEN  256
#define SEQ     200
#define SEQP    208          // padded to 13 s-tiles of 16
#define MT      13
#define VOCAB   100000

typedef _Float16 f16x8  __attribute__((ext_vector_type(8)));
typedef float    f32x4  __attribute__((ext_vector_type(4)));
typedef float    f32x2  __attribute__((ext_vector_type(2)));

// ---------------- ws layout ----------------
// [0   , 16K ) fragB8 : fp8 A-frags of 16*(W0+W2)  [tile 16][kc 2][lane 64] x 8B
// [16K , 48K ) fragW3 : f16 A-frags of 16*W3       [tile 16][kc 2][lane 64] x f16x8
// [48K , 80K ) fragDt : f16 A-frags of (W1-W2)^T   [tile 16][kc 2][lane 64] x f16x8
// [80K , 144K) fragB2 : f16 A-frags of mlp_w1      [tile 16][kc 4][lane 64] x f16x8
// [144K, 144K+6.4M) emb8: fp8(16*user_emb), row-major 64 B/vocab row (L3-resident)

// single setup kernel: weight frag packing (gid<10240) + emb8 conversion (rest)
__global__ void din_setup(const float* __restrict__ attn_w1,
                          const float* __restrict__ mlp_w1,
                          const float* __restrict__ user_emb,
                          uint2* __restrict__ fragB8,
                          _Float16* __restrict__ fragW3,
                          _Float16* __restrict__ fragDt,
                          _Float16* __restrict__ fragB2,
                          unsigned char* __restrict__ emb8,
                          int do_emb) {
  const int gid = blockIdx.x * 256 + threadIdx.x;   // [0, 110336)
  if (gid < 2048) {                                 // fragB8: fp8 16*(W0+W2)
    const int i = gid >> 7, rem = gid & 127, kc = rem >> 6, lane = rem & 63;
    const int n = i * 16 + (lane & 15);
    const int kb = kc * 32 + (lane >> 4) * 8;
    float v[8];
    #pragma unroll
    for (int j = 0; j < 8; ++j)
      v[j] = 16.0f * (attn_w1[(kb + j) * HIDDEN + n] + attn_w1[(128 + kb + j) * HIDDEN + n]);
    int lo = __builtin_amdgcn_cvt_pk_fp8_f32(v[0], v[1], 0, false);
    lo     = __builtin_amdgcn_cvt_pk_fp8_f32(v[2], v[3], lo, true);
    int hi = __builtin_amdgcn_cvt_pk_fp8_f32(v[4], v[5], 0, false);
    hi     = __builtin_amdgcn_cvt_pk_fp8_f32(v[6], v[7], hi, true);
    fragB8[gid] = uint2{(unsigned)lo, (unsigned)hi};
  } else if (gid < 4096) {                          // fragW3: f16 16*W3
    const int g = gid - 2048;
    const int i = g >> 7, rem = g & 127, kc = rem >> 6, lane = rem & 63;
    const int n = i * 16 + (lane & 15);
    const int kb = kc * 32 + (lane >> 4) * 8;
    #pragma unroll
    for (int j = 0; j < 8; ++j)
      fragW3[g * 8 + j] = (_Float16)(16.0f * attn_w1[(192 + kb + j) * HIDDEN + n]);
  } else if (gid < 6144) {                          // fragDt: f16 (W1-W2)^T A-frags
    const int g = gid - 4096;
    const int i = g >> 7, rem = g & 127, kc = rem >> 6, lane = rem & 63;
    const int n = i * 16 + (lane & 15);
    const int kb = kc * 32 + (lane >> 4) * 8;
    #pragma unroll
    for (int j = 0; j < 8; ++j)
      fragDt[g * 8 + j] = (_Float16)(attn_w1[(64 + kb + j) * HIDDEN + n]
                                   - attn_w1[(128 + kb + j) * HIDDEN + n]);
  } else if (gid < 10240) {                         // fragB2: mlp_w1 f16 A-frags
    const int g = gid - 6144;
    const int nt = g >> 8, kc = (g >> 6) & 3, lane = g & 63;
    const int n = nt * 16 + (lane & 15);
    const int kb = kc * 32 + (lane >> 4) * 8;
    #pragma unroll
    for (int j = 0; j < 8; ++j)
      fragB2[g * 8 + j] = (_Float16)mlp_w1[(kb + j) * HIDDEN + n];
  } else if (do_emb) {                              // emb8: fp8(16*user_emb), 8 elems/thread
    const int g = gid - 10240;                      // [0, 100000)
    if (g < VOCAB * EMBED / 8) {
      const int base = g * 8;
      const float4 x = *reinterpret_cast<const float4*>(&user_emb[base]);
      const float4 y = *reinterpret_cast<const float4*>(&user_emb[base + 4]);
      int lo = __builtin_amdgcn_cvt_pk_fp8_f32(16.f * x.x, 16.f * x.y, 0, false);
      lo     = __builtin_amdgcn_cvt_pk_fp8_f32(16.f * x.z, 16.f * x.w, lo, true);
      int hi = __builtin_amdgcn_cvt_pk_fp8_f32(16.f * y.x, 16.f * y.y, 0, false);
      hi     = __builtin_amdgcn_cvt_pk_fp8_f32(16.f * y.z, 16.f * y.w, hi, true);
      *reinterpret_cast<uint2*>(&emb8[base]) = uint2{(unsigned)lo, (unsigned)hi};
    }
  }
}

// ---------------- single fused kernel: one block (512 thr, 8 waves) per row ----------------
__global__ __launch_bounds__(512, 8)
void din_fused_kernel(const int* __restrict__ user_hist,
                      const int* __restrict__ target_item,
                      const float* __restrict__ user_emb,
                      const float* __restrict__ item_emb,
                      const float* __restrict__ attn_b1,
                      const float* __restrict__ attn_w2,
                      const float* __restrict__ mlp_b1,
                      const float* __restrict__ mlp_w2,
                      const float* __restrict__ mlp_b2,
                      const uint2* __restrict__ fragB8,
                      const _Float16* __restrict__ fragW3,
                      const _Float16* __restrict__ fragDt,
                      const _Float16* __restrict__ fragB2,
                      const unsigned char* __restrict__ emb8,   // may be null (ws too small)
                      float* __restrict__ out)
{
  // Hf8[st*64+lane]: 16 B = both K-chunks of fp8(16h) for (s = st*16+(lane&15),
  // quad = lane>>4): dwords {kc0.lo, kc0.hi, kc1.lo, kc1.hi}; k = kc*32+quad*8+j.
  // One ds_write_b128 / ds_read_b128 per (st,lane) - consecutive lanes 16B apart.
  __shared__ __align__(16) uint4 Hf8[MT * 64];        // 13312 B
  __shared__ __align__(16) _Float16 t16[EMBED];       // 128
  __shared__ int   histL[SEQP];                       // 832
  __shared__ float lp[8][SEQP];                       // 6656
  __shared__ float weights[SEQP];                     // 832
  __shared__ __align__(16) _Float16 mi16[EMBED];      // 128
  __shared__ float red[16];                           // 64
  // total ~22 KB

  const int b    = blockIdx.x;
  const int tid  = threadIdx.x;
  const int lane = tid & 63;
  const int wave = tid >> 6;
  const int m    = lane & 15;
  const int quad = lane >> 4;

  // ---- phase 0: target embedding + hist staging ----
  if (tid < EMBED) t16[tid] = (_Float16)item_emb[target_item[b] * EMBED + tid];
  if (tid < SEQP) histL[tid] = (tid < SEQ) ? user_hist[b * SEQ + tid] : 0;

  // static fp8 weight A-frags (global, independent of LDS)
  long long Aw8[2][2];
  #pragma unroll
  for (int i = 0; i < 2; ++i)
    #pragma unroll
    for (int c = 0; c < 2; ++c)
      Aw8[i][c] = __builtin_bit_cast(long long, fragB8[((2 * wave + i) * 2 + c) * 64 + lane]);
  __syncthreads();

  // ---- phase 1: gather h -> fp8 B-frag LDS, one b128 write per (st,lane) slot ----
  if (emb8) {
    for (int slot = tid; slot < MT * 64; slot += 512) {
      const int ln = slot & 63, st = slot >> 6;
      const int s = st * 16 + (ln & 15);
      const int q = ln >> 4;
      uint4 pv = uint4{0u, 0u, 0u, 0u};
      if (s < SEQ) {
        const unsigned char* row = &emb8[histL[s] * EMBED];
        const uint2 a = *reinterpret_cast<const uint2*>(row + q * 8);        // kc=0
        const uint2 c = *reinterpret_cast<const uint2*>(row + 32 + q * 8);   // kc=1
        pv = uint4{a.x, a.y, c.x, c.y};
      }
      Hf8[slot] = pv;
    }
  } else {
    for (int slot = tid; slot < MT * 64; slot += 512) {
      const int ln = slot & 63, st = slot >> 6;
      const int s = st * 16 + (ln & 15);
      const int q = ln >> 4;
      uint4 pv = uint4{0u, 0u, 0u, 0u};
      if (s < SEQ) {
        const float* row = &user_emb[histL[s] * EMBED];
        const float4 x0 = *reinterpret_cast<const float4*>(row + q * 8);
        const float4 y0 = *reinterpret_cast<const float4*>(row + q * 8 + 4);
        const float4 x1 = *reinterpret_cast<const float4*>(row + 32 + q * 8);
        const float4 y1 = *reinterpret_cast<const float4*>(row + 32 + q * 8 + 4);
        int a0 = __builtin_amdgcn_cvt_pk_fp8_f32(16.f * x0.x, 16.f * x0.y, 0, false);
        a0     = __builtin_amdgcn_cvt_pk_fp8_f32(16.f * x0.z, 16.f * x0.w, a0, true);
        int a1 = __builtin_amdgcn_cvt_pk_fp8_f32(16.f * y0.x, 16.f * y0.y, 0, false);
        a1     = __builtin_amdgcn_cvt_pk_fp8_f32(16.f * y0.z, 16.f * y0.w, a1, true);
        int c0 = __builtin_amdgcn_cvt_pk_fp8_f32(16.f * x1.x, 16.f * x1.y, 0, false);
        c0     = __builtin_amdgcn_cvt_pk_fp8_f32(16.f * x1.z, 16.f * x1.w, c0, true);
        int c1 = __builtin_amdgcn_cvt_pk_fp8_f32(16.f * y1.x, 16.f * y1.y, 0, false);
        c1     = __builtin_amdgcn_cvt_pk_fp8_f32(16.f * y1.z, 16.f * y1.w, c1, true);
        pv = uint4{(unsigned)a0, (unsigned)a1, (unsigned)c0, (unsigned)c1};
      }
      Hf8[slot] = pv;
    }
  }

  // ---- phase 2 (overlaps gather VMEM drain; touches only t16 + global frags) ----
  const f16x8 tv0 = *reinterpret_cast<const f16x8*>(&t16[quad * 8]);
  const f16x8 tv1 = *reinterpret_cast<const f16x8*>(&t16[32 + quad * 8]);

  long long AwT[2][2];
  #pragma unroll
  for (int i = 0; i < 2; ++i) {
    #pragma unroll
    for (int c = 0; c < 2; ++c) {
      const f16x8 w3v = reinterpret_cast<const f16x8*>(fragW3)[((2 * wave + i) * 2 + c) * 64 + lane];
      const f16x8 p = w3v * (c ? tv1 : tv0);
      int lo = __builtin_amdgcn_cvt_pk_fp8_f32((float)p[0], (float)p[1], 0, false);
      lo     = __builtin_amdgcn_cvt_pk_fp8_f32((float)p[2], (float)p[3], lo, true);
      int hi = __builtin_amdgcn_cvt_pk_fp8_f32((float)p[4], (float)p[5], 0, false);
      hi     = __builtin_amdgcn_cvt_pk_fp8_f32((float)p[6], (float)p[7], hi, true);
      AwT[i][c] = __builtin_bit_cast(long long, uint2{(unsigned)lo, (unsigned)hi});
    }
  }

  // c-fold: c[n] = b1[n] + sum_k t[k] D[k][n]; A = D^T frags, B = broadcast t
  float cn[2][4], w2n[2][4];
  #pragma unroll
  for (int i = 0; i < 2; ++i) {
    const int tile = 2 * wave + i;
    const f16x8 d0 = reinterpret_cast<const f16x8*>(fragDt)[(tile * 2 + 0) * 64 + lane];
    const f16x8 d1 = reinterpret_cast<const f16x8*>(fragDt)[(tile * 2 + 1) * 64 + lane];
    f32x4 acc = {0.f, 0.f, 0.f, 0.f};
    acc = __builtin_amdgcn_mfma_f32_16x16x32_f16(d0, tv0, acc, 0, 0, 0);
    acc = __builtin_amdgcn_mfma_f32_16x16x32_f16(d1, tv1, acc, 0, 0, 0);
    const int nb = tile * 16 + quad * 4;
    const float4 b1v = *reinterpret_cast<const float4*>(&attn_b1[nb]);
    const float4 w2v = *reinterpret_cast<const float4*>(&attn_w2[nb]);
    cn[i][0] = 256.0f * (b1v.x + acc[0]);
    cn[i][1] = 256.0f * (b1v.y + acc[1]);
    cn[i][2] = 256.0f * (b1v.z + acc[2]);
    cn[i][3] = 256.0f * (b1v.w + acc[3]);
    w2n[i][0] = w2v.x * (1.0f / 256.0f);
    w2n[i][1] = w2v.y * (1.0f / 256.0f);
    w2n[i][2] = w2v.z * (1.0f / 256.0f);
    w2n[i][3] = w2v.w * (1.0f / 256.0f);
  }
  __syncthreads();

  // ---- phase 3: fp8 K=128 MFMA GEMM (H^T); one ds_read_b128 per st ----
  #pragma unroll 2
  for (int st = 0; st < MT; ++st) {
    const uint4 hv = Hf8[st * 64 + lane];
    const long long b0 = __builtin_bit_cast(long long, uint2{hv.x, hv.y});
    const long long b1 = __builtin_bit_cast(long long, uint2{hv.z, hv.w});
    float lg = 0.f;
    #pragma unroll
    for (int i = 0; i < 2; ++i) {
      f32x4 acc = {cn[i][0], cn[i][1], cn[i][2], cn[i][3]};
      acc = __builtin_amdgcn_mfma_f32_16x16x32_fp8_fp8(Aw8[i][0], b0, acc, 0, 0, 0);
      acc = __builtin_amdgcn_mfma_f32_16x16x32_fp8_fp8(Aw8[i][1], b1, acc, 0, 0, 0);
      acc = __builtin_amdgcn_mfma_f32_16x16x32_fp8_fp8(AwT[i][0], b0, acc, 0, 0, 0);
      acc = __builtin_amdgcn_mfma_f32_16x16x32_fp8_fp8(AwT[i][1], b1, acc, 0, 0, 0);
      #pragma unroll
      for (int r = 0; r < 4; ++r)
        lg += fmaxf(acc[r], 0.0f) * w2n[i][r];
    }
    lg += __shfl_xor(lg, 16, 64);
    lg += __shfl_xor(lg, 32, 64);
    if (lane < 16) lp[wave][st * 16 + lane] = lg;
  }
  __syncthreads();

  // ---- phase 4: softmax over SEQ on waves 0-3 only (uniform barriers) ----
  float v = -INFINITY, e = 0.0f;
  if (wave < 4) {
    if (tid < SEQ)
      v = lp[0][tid] + lp[1][tid] + lp[2][tid] + lp[3][tid]
        + lp[4][tid] + lp[5][tid] + lp[6][tid] + lp[7][tid];
    float mx = v;
    #pragma unroll
    for (int off = 32; off; off >>= 1) mx = fmaxf(mx, __shfl_xor(mx, off, 64));
    if (lane == 0) red[wave] = mx;
  }
  __syncthreads();
  if (wave < 4) {
    const float mx = fmaxf(fmaxf(red[0], red[1]), fmaxf(red[2], red[3]));
    e = (tid < SEQ) ? expf(v - mx) : 0.0f;
    float ssum = e;
    #pragma unroll
    for (int off = 32; off; off >>= 1) ssum += __shfl_xor(ssum, off, 64);
    if (lane == 0) red[4 + wave] = ssum;
  }
  __syncthreads();
  if (wave < 4) {
    const float tot = red[4] + red[5] + red[6] + red[7];
    if (tid < SEQP) weights[tid] = (tid < SEQ) ? e / tot : 0.0f;
  }
  __syncthreads();

  // ---- phase 5: weighted interest pooling; wave -> (kc = w&1, st-group = w>>1) ----
  {
    const int kc = wave & 1, g = wave >> 1;
    float pk[8];
    #pragma unroll
    for (int j = 0; j < 8; ++j) pk[j] = 0.f;
    #pragma unroll
    for (int st2 = 0; st2 < 4; ++st2) {
      const int st = g + st2 * 4;
      if (st < MT) {
        const float wt = weights[st * 16 + m];
        const uint4 hq = Hf8[st * 64 + lane];      // full b128: conflict-free
        const unsigned lo = kc ? hq.z : hq.x;
        const unsigned hi = kc ? hq.w : hq.y;
        const f32x2 f0 = __builtin_amdgcn_cvt_pk_f32_fp8((int)lo, false);
        const f32x2 f1 = __builtin_amdgcn_cvt_pk_f32_fp8((int)lo, true);
        const f32x2 f2 = __builtin_amdgcn_cvt_pk_f32_fp8((int)hi, false);
        const f32x2 f3 = __builtin_amdgcn_cvt_pk_f32_fp8((int)hi, true);
        pk[0] += wt * f0.x;  pk[1] += wt * f0.y;
        pk[2] += wt * f1.x;  pk[3] += wt * f1.y;
        pk[4] += wt * f2.x;  pk[5] += wt * f2.y;
        pk[6] += wt * f3.x;  pk[7] += wt * f3.y;
      }
    }
    #pragma unroll
    for (int j = 0; j < 8; ++j) {
      float p = pk[j];
      p += __shfl_xor(p, 1, 64);
      p += __shfl_xor(p, 2, 64);
      p += __shfl_xor(p, 4, 64);
      p += __shfl_xor(p, 8, 64);
      pk[j] = p;
    }
    if (m == 0) {
      #pragma unroll
      for (int j = 0; j < 8; ++j)
        lp[g][kc * 32 + quad * 8 + j] = pk[j];     // lp reused: interest partials (16x-scaled)
    }
  }
  __syncthreads();
  if (tid < EMBED)
    mi16[tid] = (_Float16)((lp[0][tid] + lp[1][tid] + lp[2][tid] + lp[3][tid]) * 0.0625f);
  __syncthreads();

  // ---- phase 6: prediction head, f16 MFMA, broadcast-B ----
  {
    const f16x8 mb0 = *reinterpret_cast<const f16x8*>(&mi16[quad * 8]);
    const f16x8 mb1 = *reinterpret_cast<const f16x8*>(&mi16[32 + quad * 8]);
    float z = 0.f;
    #pragma unroll
    for (int i = 0; i < 2; ++i) {
      const f16x8* B2 = reinterpret_cast<const f16x8*>(fragB2) + ((2 * wave + i) * 4) * 64 + lane;
      const int nb = (2 * wave + i) * 16 + quad * 4;
      const float4 bb = *reinterpret_cast<const float4*>(&mlp_b1[nb]);
      const float4 ww = *reinterpret_cast<const float4*>(&mlp_w2[nb]);
      f32x4 acc = {bb.x, bb.y, bb.z, bb.w};
      acc = __builtin_amdgcn_mfma_f32_16x16x32_f16(B2[0],   mb0, acc, 0, 0, 0);
      acc = __builtin_amdgcn_mfma_f32_16x16x32_f16(B2[64],  mb1, acc, 0, 0, 0);
      acc = __builtin_amdgcn_mfma_f32_16x16x32_f16(B2[128], tv0, acc, 0, 0, 0);
      acc = __builtin_amdgcn_mfma_f32_16x16x32_f16(B2[192], tv1, acc, 0, 0, 0);
      z += fmaxf(acc[0], 0.0f) * ww.x;
      z += fmaxf(acc[1], 0.0f) * ww.y;
      z += fmaxf(acc[2], 0.0f) * ww.z;
      z += fmaxf(acc[3], 0.0f) * ww.w;
    }
    z += __shfl_xor(z, 16, 64);
    z += __shfl_xor(z, 32, 64);
    if (lane == 0) red[wave] = z;
  }
  __syncthreads();
  if (tid == 0) {
    const float zz = red[0] + red[1] + red[2] + red[3]
                   + red[4] + red[5] + red[6] + red[7] + mlp_b2[0];
    out[b] = 1.0f / (1.0f + expf(-zz));
  }
}

extern "C" void kernel_launch(void* const* d_in, const int* in_sizes, int n_in,
                              void* d_out, int out_size, void* d_ws, size_t ws_size,
                              hipStream_t stream) {
  const int*   user_hist   = (const int*)  d_in[0];
  const int*   target_item = (const int*)  d_in[1];
  const float* user_emb    = (const float*)d_in[2];
  const float* item_emb    = (const float*)d_in[3];
  const float* attn_w1     = (const float*)d_in[4];
  const float* attn_b1     = (const float*)d_in[5];
  const float* attn_w2     = (const float*)d_in[6];
  // d_in[7] = attn_b2: constant shift on logits -> cancels in softmax
  const float* mlp_w1      = (const float*)d_in[8];
  const float* mlp_b1      = (const float*)d_in[9];
  const float* mlp_w2      = (const float*)d_in[10];
  const float* mlp_b2      = (const float*)d_in[11];
  float* out = (float*)d_out;

  uint2*    fragB8 = (uint2*)d_ws;                           // 16 KB
  _Float16* fragW3 = (_Float16*)((char*)d_ws + 16384);       // 32 KB
  _Float16* fragDt = (_Float16*)((char*)d_ws + 49152);       // 32 KB
  _Float16* fragB2 = (_Float16*)((char*)d_ws + 81920);       // 64 KB
  const size_t emb8_off = 147456;
  const size_t emb8_bytes = (size_t)VOCAB * EMBED;           // 6.4 MB
  unsigned char* emb8 = nullptr;
  if (ws_size >= emb8_off + emb8_bytes)                      // ws_size is call-invariant: capture-safe
    emb8 = (unsigned char*)d_ws + emb8_off;

  // one setup launch: frag packing (gids 0..10239) + emb8 conversion (rest)
  const int setup_gids = 10240 + VOCAB * EMBED / 8;          // 110240
  din_setup<<<(setup_gids + 255) / 256, 256, 0, stream>>>(
      attn_w1, mlp_w1, user_emb, fragB8, fragW3, fragDt, fragB2,
      emb8 ? emb8 : (unsigned char*)d_ws, emb8 ? 1 : 0);

  const int batch = in_sizes[1];
  din_fused_kernel<<<batch, 512, 0, stream>>>(
      user_hist, target_item, user_emb, item_emb,
      attn_b1, attn_w2, mlp_b1, mlp_w2, mlp_b2,
      fragB8, fragW3, fragDt, fragB2, emb8, out);
}

// Round 12
// 174.113 us; speedup vs baseline: 1.0959x; 1.0959x over previous
//
#include <hip/hip_runtime.h>
#include <math.h>

#define EMBED   64
#define HIDDEN  256
#define SEQ     200
#define SEQP    208          // padded to 13 s-tiles of 16
#define MT      13
#define VOCAB   100000

typedef _Float16 f16x8  __attribute__((ext_vector_type(8)));
typedef float    f32x4  __attribute__((ext_vector_type(4)));
typedef float    f32x2  __attribute__((ext_vector_type(2)));

// ---------------- ws layout ----------------
// [0   , 16K ) fragB8 : fp8 A-frags of 16*(W0+W2)  [tile 16][kc 2][lane 64] x 8B
// [16K , 48K ) fragW3 : f16 A-frags of 16*W3       [tile 16][kc 2][lane 64] x f16x8
// [48K , 80K ) fragDt : f16 A-frags of (W1-W2)^T   [tile 16][kc 2][lane 64] x f16x8
// [80K , 144K) fragB2 : f16 A-frags of mlp_w1      [tile 16][kc 4][lane 64] x f16x8
// [144K, 144K+6.4M) emb8: fp8(16*user_emb), row-major 64 B/vocab row (L3-resident)

// single setup kernel: weight frag packing (gid<10240) + emb8 conversion (rest)
__global__ void din_setup(const float* __restrict__ attn_w1,
                          const float* __restrict__ mlp_w1,
                          const float* __restrict__ user_emb,
                          uint2* __restrict__ fragB8,
                          _Float16* __restrict__ fragW3,
                          _Float16* __restrict__ fragDt,
                          _Float16* __restrict__ fragB2,
                          unsigned char* __restrict__ emb8,
                          int do_emb) {
  const int gid = blockIdx.x * 256 + threadIdx.x;   // [0, 110336)
  if (gid < 2048) {                                 // fragB8: fp8 16*(W0+W2)
    const int i = gid >> 7, rem = gid & 127, kc = rem >> 6, lane = rem & 63;
    const int n = i * 16 + (lane & 15);
    const int kb = kc * 32 + (lane >> 4) * 8;
    float v[8];
    #pragma unroll
    for (int j = 0; j < 8; ++j)
      v[j] = 16.0f * (attn_w1[(kb + j) * HIDDEN + n] + attn_w1[(128 + kb + j) * HIDDEN + n]);
    int lo = __builtin_amdgcn_cvt_pk_fp8_f32(v[0], v[1], 0, false);
    lo     = __builtin_amdgcn_cvt_pk_fp8_f32(v[2], v[3], lo, true);
    int hi = __builtin_amdgcn_cvt_pk_fp8_f32(v[4], v[5], 0, false);
    hi     = __builtin_amdgcn_cvt_pk_fp8_f32(v[6], v[7], hi, true);
    fragB8[gid] = uint2{(unsigned)lo, (unsigned)hi};
  } else if (gid < 4096) {                          // fragW3: f16 16*W3
    const int g = gid - 2048;
    const int i = g >> 7, rem = g & 127, kc = rem >> 6, lane = rem & 63;
    const int n = i * 16 + (lane & 15);
    const int kb = kc * 32 + (lane >> 4) * 8;
    #pragma unroll
    for (int j = 0; j < 8; ++j)
      fragW3[g * 8 + j] = (_Float16)(16.0f * attn_w1[(192 + kb + j) * HIDDEN + n]);
  } else if (gid < 6144) {                          // fragDt: f16 (W1-W2)^T A-frags
    const int g = gid - 4096;
    const int i = g >> 7, rem = g & 127, kc = rem >> 6, lane = rem & 63;
    const int n = i * 16 + (lane & 15);
    const int kb = kc * 32 + (lane >> 4) * 8;
    #pragma unroll
    for (int j = 0; j < 8; ++j)
      fragDt[g * 8 + j] = (_Float16)(attn_w1[(64 + kb + j) * HIDDEN + n]
                                   - attn_w1[(128 + kb + j) * HIDDEN + n]);
  } else if (gid < 10240) {                         // fragB2: mlp_w1 f16 A-frags
    const int g = gid - 6144;
    const int nt = g >> 8, kc = (g >> 6) & 3, lane = g & 63;
    const int n = nt * 16 + (lane & 15);
    const int kb = kc * 32 + (lane >> 4) * 8;
    #pragma unroll
    for (int j = 0; j < 8; ++j)
      fragB2[g * 8 + j] = (_Float16)mlp_w1[(kb + j) * HIDDEN + n];
  } else if (do_emb) {                              // emb8: fp8(16*user_emb), 8 elems/thread
    const int g = gid - 10240;                      // [0, 800000)
    if (g < VOCAB * EMBED / 8) {
      const int base = g * 8;
      const float4 x = *reinterpret_cast<const float4*>(&user_emb[base]);
      const float4 y = *reinterpret_cast<const float4*>(&user_emb[base + 4]);
      int lo = __builtin_amdgcn_cvt_pk_fp8_f32(16.f * x.x, 16.f * x.y, 0, false);
      lo     = __builtin_amdgcn_cvt_pk_fp8_f32(16.f * x.z, 16.f * x.w, lo, true);
      int hi = __builtin_amdgcn_cvt_pk_fp8_f32(16.f * y.x, 16.f * y.y, 0, false);
      hi     = __builtin_amdgcn_cvt_pk_fp8_f32(16.f * y.z, 16.f * y.w, hi, true);
      *reinterpret_cast<uint2*>(&emb8[base]) = uint2{(unsigned)lo, (unsigned)hi};
    }
  }
}

// ---------------- single fused kernel: one block (512 thr, 8 waves) per row ----------------
// R10-proven structure. NOTE: at launch_bounds(512,8) the kernel sits exactly at the
// 64-VGPR ceiling - widening any per-thread path (e.g. uint4 LDS slots, R11) spills
// to scratch (WRITE_SIZE 128 KB -> 112 MB, dur 82 -> 107 us). Keep b64-based slots.
__global__ __launch_bounds__(512, 8)
void din_fused_kernel(const int* __restrict__ user_hist,
                      const int* __restrict__ target_item,
                      const float* __restrict__ user_emb,
                      const float* __restrict__ item_emb,
                      const float* __restrict__ attn_b1,
                      const float* __restrict__ attn_w2,
                      const float* __restrict__ mlp_b1,
                      const float* __restrict__ mlp_w2,
                      const float* __restrict__ mlp_b2,
                      const uint2* __restrict__ fragB8,
                      const _Float16* __restrict__ fragW3,
                      const _Float16* __restrict__ fragDt,
                      const _Float16* __restrict__ fragB2,
                      const unsigned char* __restrict__ emb8,   // may be null (ws too small)
                      float* __restrict__ out)
{
  __shared__ __align__(16) uint2 Hf8[MT * 2 * 64];    // 13312 B, fp8(16h) B-frags
  __shared__ __align__(16) _Float16 t16[EMBED];       // 128
  __shared__ int   histL[SEQP];                       // 832
  __shared__ float lp[8][SEQP];                       // 6656
  __shared__ float weights[SEQP];                     // 832
  __shared__ __align__(16) _Float16 mi16[EMBED];      // 128
  __shared__ float red[16];                           // 64
  // total ~22 KB

  const int b    = blockIdx.x;
  const int tid  = threadIdx.x;
  const int lane = tid & 63;
  const int wave = tid >> 6;
  const int m    = lane & 15;
  const int quad = lane >> 4;

  // ---- phase 0: target embedding + hist staging ----
  if (tid < EMBED) t16[tid] = (_Float16)item_emb[target_item[b] * EMBED + tid];
  if (tid < SEQP) histL[tid] = (tid < SEQ) ? user_hist[b * SEQ + tid] : 0;

  // static fp8 weight A-frags (global, independent of LDS)
  long long Aw8[2][2];
  #pragma unroll
  for (int i = 0; i < 2; ++i)
    #pragma unroll
    for (int c = 0; c < 2; ++c)
      Aw8[i][c] = __builtin_bit_cast(long long, fragB8[((2 * wave + i) * 2 + c) * 64 + lane]);
  __syncthreads();

  // ---- phase 1: gather h -> fp8 B-frag LDS ----
  // fast path: emb8 table already holds fp8(16h) -> one 8 B load, no cvt/mul
  if (emb8) {
    for (int slot = tid; slot < MT * 2 * 64; slot += 512) {
      const int ln = slot & 63, kcomb = slot >> 6;
      const int st = kcomb >> 1, kc = kcomb & 1;
      const int s = st * 16 + (ln & 15);
      const int kb = kc * 32 + (ln >> 4) * 8;
      uint2 pv = uint2{0u, 0u};
      if (s < SEQ)
        pv = *reinterpret_cast<const uint2*>(&emb8[histL[s] * EMBED + kb]);
      Hf8[slot] = pv;
    }
  } else {
    for (int slot = tid; slot < MT * 2 * 64; slot += 512) {
      const int ln = slot & 63, kcomb = slot >> 6;
      const int st = kcomb >> 1, kc = kcomb & 1;
      const int s = st * 16 + (ln & 15);
      const int kb = kc * 32 + (ln >> 4) * 8;
      uint2 pv = uint2{0u, 0u};
      if (s < SEQ) {
        const float4* src = reinterpret_cast<const float4*>(&user_emb[histL[s] * EMBED + kb]);
        const float4 x = src[0], y = src[1];
        int lo = __builtin_amdgcn_cvt_pk_fp8_f32(16.f * x.x, 16.f * x.y, 0, false);
        lo     = __builtin_amdgcn_cvt_pk_fp8_f32(16.f * x.z, 16.f * x.w, lo, true);
        int hi = __builtin_amdgcn_cvt_pk_fp8_f32(16.f * y.x, 16.f * y.y, 0, false);
        hi     = __builtin_amdgcn_cvt_pk_fp8_f32(16.f * y.z, 16.f * y.w, hi, true);
        pv = uint2{(unsigned)lo, (unsigned)hi};
      }
      Hf8[slot] = pv;
    }
  }

  // ---- phase 2 (overlaps gather VMEM drain; touches only t16 + global frags) ----
  const f16x8 tv0 = *reinterpret_cast<const f16x8*>(&t16[quad * 8]);
  const f16x8 tv1 = *reinterpret_cast<const f16x8*>(&t16[32 + quad * 8]);

  long long AwT[2][2];
  #pragma unroll
  for (int i = 0; i < 2; ++i) {
    #pragma unroll
    for (int c = 0; c < 2; ++c) {
      const f16x8 w3v = reinterpret_cast<const f16x8*>(fragW3)[((2 * wave + i) * 2 + c) * 64 + lane];
      const f16x8 p = w3v * (c ? tv1 : tv0);
      int lo = __builtin_amdgcn_cvt_pk_fp8_f32((float)p[0], (float)p[1], 0, false);
      lo     = __builtin_amdgcn_cvt_pk_fp8_f32((float)p[2], (float)p[3], lo, true);
      int hi = __builtin_amdgcn_cvt_pk_fp8_f32((float)p[4], (float)p[5], 0, false);
      hi     = __builtin_amdgcn_cvt_pk_fp8_f32((float)p[6], (float)p[7], hi, true);
      AwT[i][c] = __builtin_bit_cast(long long, uint2{(unsigned)lo, (unsigned)hi});
    }
  }

  // c-fold: c[n] = b1[n] + sum_k t[k] D[k][n]; A = D^T frags, B = broadcast t
  float cn[2][4], w2n[2][4];
  #pragma unroll
  for (int i = 0; i < 2; ++i) {
    const int tile = 2 * wave + i;
    const f16x8 d0 = reinterpret_cast<const f16x8*>(fragDt)[(tile * 2 + 0) * 64 + lane];
    const f16x8 d1 = reinterpret_cast<const f16x8*>(fragDt)[(tile * 2 + 1) * 64 + lane];
    f32x4 acc = {0.f, 0.f, 0.f, 0.f};
    acc = __builtin_amdgcn_mfma_f32_16x16x32_f16(d0, tv0, acc, 0, 0, 0);
    acc = __builtin_amdgcn_mfma_f32_16x16x32_f16(d1, tv1, acc, 0, 0, 0);
    const int nb = tile * 16 + quad * 4;
    const float4 b1v = *reinterpret_cast<const float4*>(&attn_b1[nb]);
    const float4 w2v = *reinterpret_cast<const float4*>(&attn_w2[nb]);
    cn[i][0] = 256.0f * (b1v.x + acc[0]);
    cn[i][1] = 256.0f * (b1v.y + acc[1]);
    cn[i][2] = 256.0f * (b1v.z + acc[2]);
    cn[i][3] = 256.0f * (b1v.w + acc[3]);
    w2n[i][0] = w2v.x * (1.0f / 256.0f);
    w2n[i][1] = w2v.y * (1.0f / 256.0f);
    w2n[i][2] = w2v.z * (1.0f / 256.0f);
    w2n[i][3] = w2v.w * (1.0f / 256.0f);
  }
  __syncthreads();

  // ---- phase 3: fp8 K=128 MFMA GEMM (H^T); wave owns n-tiles 2w, 2w+1 ----
  #pragma unroll 2
  for (int st = 0; st < MT; ++st) {
    const long long b0 = __builtin_bit_cast(long long, Hf8[(st * 2 + 0) * 64 + lane]);
    const long long b1 = __builtin_bit_cast(long long, Hf8[(st * 2 + 1) * 64 + lane]);
    float lg = 0.f;
    #pragma unroll
    for (int i = 0; i < 2; ++i) {
      f32x4 acc = {cn[i][0], cn[i][1], cn[i][2], cn[i][3]};
      acc = __builtin_amdgcn_mfma_f32_16x16x32_fp8_fp8(Aw8[i][0], b0, acc, 0, 0, 0);
      acc = __builtin_amdgcn_mfma_f32_16x16x32_fp8_fp8(Aw8[i][1], b1, acc, 0, 0, 0);
      acc = __builtin_amdgcn_mfma_f32_16x16x32_fp8_fp8(AwT[i][0], b0, acc, 0, 0, 0);
      acc = __builtin_amdgcn_mfma_f32_16x16x32_fp8_fp8(AwT[i][1], b1, acc, 0, 0, 0);
      #pragma unroll
      for (int r = 0; r < 4; ++r)
        lg += fmaxf(acc[r], 0.0f) * w2n[i][r];
    }
    lg += __shfl_xor(lg, 16, 64);
    lg += __shfl_xor(lg, 32, 64);
    if (lane < 16) lp[wave][st * 16 + lane] = lg;
  }
  __syncthreads();

  // ---- phase 4: softmax over SEQ on waves 0-3 only (uniform barriers) ----
  float v = -INFINITY, e = 0.0f;
  if (wave < 4) {
    if (tid < SEQ)
      v = lp[0][tid] + lp[1][tid] + lp[2][tid] + lp[3][tid]
        + lp[4][tid] + lp[5][tid] + lp[6][tid] + lp[7][tid];
    float mx = v;
    #pragma unroll
    for (int off = 32; off; off >>= 1) mx = fmaxf(mx, __shfl_xor(mx, off, 64));
    if (lane == 0) red[wave] = mx;
  }
  __syncthreads();
  if (wave < 4) {
    const float mx = fmaxf(fmaxf(red[0], red[1]), fmaxf(red[2], red[3]));
    e = (tid < SEQ) ? expf(v - mx) : 0.0f;
    float ssum = e;
    #pragma unroll
    for (int off = 32; off; off >>= 1) ssum += __shfl_xor(ssum, off, 64);
    if (lane == 0) red[4 + wave] = ssum;
  }
  __syncthreads();
  if (wave < 4) {
    const float tot = red[4] + red[5] + red[6] + red[7];
    if (tid < SEQP) weights[tid] = (tid < SEQ) ? e / tot : 0.0f;
  }
  __syncthreads();

  // ---- phase 5: weighted interest pooling; wave -> (kc = w&1, st-group = w>>1) ----
  {
    const int kc = wave & 1, g = wave >> 1;
    float pk[8];
    #pragma unroll
    for (int j = 0; j < 8; ++j) pk[j] = 0.f;
    #pragma unroll
    for (int st2 = 0; st2 < 4; ++st2) {
      const int st = g + st2 * 4;
      if (st < MT) {
        const float wt = weights[st * 16 + m];
        const uint2 hv = Hf8[(st * 2 + kc) * 64 + lane];
        const f32x2 f0 = __builtin_amdgcn_cvt_pk_f32_fp8((int)hv.x, false);
        const f32x2 f1 = __builtin_amdgcn_cvt_pk_f32_fp8((int)hv.x, true);
        const f32x2 f2 = __builtin_amdgcn_cvt_pk_f32_fp8((int)hv.y, false);
        const f32x2 f3 = __builtin_amdgcn_cvt_pk_f32_fp8((int)hv.y, true);
        pk[0] += wt * f0.x;  pk[1] += wt * f0.y;
        pk[2] += wt * f1.x;  pk[3] += wt * f1.y;
        pk[4] += wt * f2.x;  pk[5] += wt * f2.y;
        pk[6] += wt * f3.x;  pk[7] += wt * f3.y;
      }
    }
    #pragma unroll
    for (int j = 0; j < 8; ++j) {
      float p = pk[j];
      p += __shfl_xor(p, 1, 64);
      p += __shfl_xor(p, 2, 64);
      p += __shfl_xor(p, 4, 64);
      p += __shfl_xor(p, 8, 64);
      pk[j] = p;
    }
    if (m == 0) {
      #pragma unroll
      for (int j = 0; j < 8; ++j)
        lp[g][kc * 32 + quad * 8 + j] = pk[j];     // lp reused: interest partials (16x-scaled)
    }
  }
  __syncthreads();
  if (tid < EMBED)
    mi16[tid] = (_Float16)((lp[0][tid] + lp[1][tid] + lp[2][tid] + lp[3][tid]) * 0.0625f);
  __syncthreads();

  // ---- phase 6: prediction head, f16 MFMA, broadcast-B ----
  {
    const f16x8 mb0 = *reinterpret_cast<const f16x8*>(&mi16[quad * 8]);
    const f16x8 mb1 = *reinterpret_cast<const f16x8*>(&mi16[32 + quad * 8]);
    float z = 0.f;
    #pragma unroll
    for (int i = 0; i < 2; ++i) {
      const f16x8* B2 = reinterpret_cast<const f16x8*>(fragB2) + ((2 * wave + i) * 4) * 64 + lane;
      const int nb = (2 * wave + i) * 16 + quad * 4;
      const float4 bb = *reinterpret_cast<const float4*>(&mlp_b1[nb]);
      const float4 ww = *reinterpret_cast<const float4*>(&mlp_w2[nb]);
      f32x4 acc = {bb.x, bb.y, bb.z, bb.w};
      acc = __builtin_amdgcn_mfma_f32_16x16x32_f16(B2[0],   mb0, acc, 0, 0, 0);
      acc = __builtin_amdgcn_mfma_f32_16x16x32_f16(B2[64],  mb1, acc, 0, 0, 0);
      acc = __builtin_amdgcn_mfma_f32_16x16x32_f16(B2[128], tv0, acc, 0, 0, 0);
      acc = __builtin_amdgcn_mfma_f32_16x16x32_f16(B2[192], tv1, acc, 0, 0, 0);
      z += fmaxf(acc[0], 0.0f) * ww.x;
      z += fmaxf(acc[1], 0.0f) * ww.y;
      z += fmaxf(acc[2], 0.0f) * ww.z;
      z += fmaxf(acc[3], 0.0f) * ww.w;
    }
    z += __shfl_xor(z, 16, 64);
    z += __shfl_xor(z, 32, 64);
    if (lane == 0) red[wave] = z;
  }
  __syncthreads();
  if (tid == 0) {
    const float zz = red[0] + red[1] + red[2] + red[3]
                   + red[4] + red[5] + red[6] + red[7] + mlp_b2[0];
    out[b] = 1.0f / (1.0f + expf(-zz));
  }
}

extern "C" void kernel_launch(void* const* d_in, const int* in_sizes, int n_in,
                              void* d_out, int out_size, void* d_ws, size_t ws_size,
                              hipStream_t stream) {
  const int*   user_hist   = (const int*)  d_in[0];
  const int*   target_item = (const int*)  d_in[1];
  const float* user_emb    = (const float*)d_in[2];
  const float* item_emb    = (const float*)d_in[3];
  const float* attn_w1     = (const float*)d_in[4];
  const float* attn_b1     = (const float*)d_in[5];
  const float* attn_w2     = (const float*)d_in[6];
  // d_in[7] = attn_b2: constant shift on logits -> cancels in softmax
  const float* mlp_w1      = (const float*)d_in[8];
  const float* mlp_b1      = (const float*)d_in[9];
  const float* mlp_w2      = (const float*)d_in[10];
  const float* mlp_b2      = (const float*)d_in[11];
  float* out = (float*)d_out;

  uint2*    fragB8 = (uint2*)d_ws;                           // 16 KB
  _Float16* fragW3 = (_Float16*)((char*)d_ws + 16384);       // 32 KB
  _Float16* fragDt = (_Float16*)((char*)d_ws + 49152);       // 32 KB
  _Float16* fragB2 = (_Float16*)((char*)d_ws + 81920);       // 64 KB
  const size_t emb8_off = 147456;
  const size_t emb8_bytes = (size_t)VOCAB * EMBED;           // 6.4 MB
  unsigned char* emb8 = nullptr;
  if (ws_size >= emb8_off + emb8_bytes)                      // ws_size is call-invariant: capture-safe
    emb8 = (unsigned char*)d_ws + emb8_off;

  // one setup launch: frag packing (gids 0..10239) + emb8 conversion (rest)
  const int setup_gids = 10240 + VOCAB * EMBED / 8;          // 110240
  din_setup<<<(setup_gids + 255) / 256, 256, 0, stream>>>(
      attn_w1, mlp_w1, user_emb, fragB8, fragW3, fragDt, fragB2,
      emb8 ? emb8 : (unsigned char*)d_ws, emb8 ? 1 : 0);

  const int batch = in_sizes[1];
  din_fused_kernel<<<batch, 512, 0, stream>>>(
      user_hist, target_item, user_emb, item_emb,
      attn_b1, attn_w2, mlp_b1, mlp_w2, mlp_b2,
      fragB8, fragW3, fragDt, fragB2, emb8, out);
}